// Round 2
// baseline (628.205 us; speedup 1.0000x reference)
//
#include <hip/hip_runtime.h>
#include <hip/hip_bf16.h>
#include <stdint.h>

// DEQTrellisNetLM on MI355X (gfx950).
// B=4, L=1024, H=768, 4H=3072, NINP=512, K=2, NLAYER=10, NOUT=256.
//
//  - h time-major (B,L+1,H) bf16; c time-major (B,L+1,H) fp16. Row 0 = z0.
//  - Weights pre-permuted (N,K) bf16, gate-interleaved cols o'=(j>>4)*64+gate*16+(j&15).
//  - us precomputed once as fp16x4 gate-gathered: us4[m][j] = {i,o,g,f} (+ both biases).
//  - Last iteration computes only the NOUT-needed column range; tiny tail kernel
//    computes full-channel state at t=L for z0_out.

#define B_    4
#define L_    1024
#define LP1   1025
#define H_    768
#define NG_   3072
#define NINP_ 512
#define NOUT_ 256

typedef __bf16 bf16x8 __attribute__((ext_vector_type(8)));
typedef float f32x4 __attribute__((ext_vector_type(4)));
typedef _Float16 f16x4 __attribute__((ext_vector_type(4)));
using bf16_t = __hip_bfloat16;

__device__ __forceinline__ float sigf(float x){ return 1.f/(1.f + __expf(-x)); }
__device__ __forceinline__ float tanhf_(float x){
  float e = __expf(-2.f*fabsf(x));
  float r = (1.f - e)/(1.f + e);
  return x >= 0.f ? r : -r;
}

__device__ __forceinline__ void gl_lds16(const void* g, void* l){
  __builtin_amdgcn_global_load_lds(
    (const __attribute__((address_space(1))) uint32_t*)g,
    (__attribute__((address_space(3))) uint32_t*)l, 16, 0, 0);
}

// ---- init: zero Xt row0, set h/c row0 from z0 ----
__global__ void init_k(const float* __restrict__ z0, bf16_t* __restrict__ Xt,
                       bf16_t* __restrict__ Hb0, bf16_t* __restrict__ Hb1,
                       _Float16* __restrict__ Cb0, _Float16* __restrict__ Cb1){
  int tid = blockIdx.x*256 + threadIdx.x;
  if (tid < B_*NINP_){
    int b = tid >> 9, i = tid & 511;
    Xt[(size_t)b*LP1*NINP_ + i] = __float2bfloat16(0.f);
  }
  if (tid < B_*H_){
    int b = tid / H_, j = tid % H_;
    size_t idx = (size_t)b*LP1*H_ + j;
    bf16_t hz = __float2bfloat16(z0[b*2*H_ + j]);
    _Float16 cz = (_Float16)z0[b*2*H_ + H_ + j];
    Hb0[idx] = hz; Hb1[idx] = hz; Cb0[idx] = cz; Cb1[idx] = cz;
  }
}

// ---- weight prep: permute + transpose + bf16; biases gathered per-j float4 ----
__global__ void prep_w(const float* __restrict__ iw, const float* __restrict__ ib,
                       const float* __restrict__ cw, const float* __restrict__ cb,
                       bf16_t* __restrict__ Wit, bf16_t* __restrict__ Wct,
                       float* __restrict__ bias4){
  int op = blockIdx.x;
  int gate = (op >> 4) & 3;
  int j = ((op >> 6) << 4) | (op & 15);
  int o = gate*H_ + j;
  const float2* s2 = (const float2*)(iw + (size_t)o*NINP_*2);
  bf16_t* d = Wit + (size_t)op*(2*NINP_);
  for (int i = threadIdx.x; i < NINP_; i += 256){
    float2 v = s2[i];
    d[i]         = __float2bfloat16(v.x);   // tap k=0 (t-1)
    d[NINP_ + i] = __float2bfloat16(v.y);   // tap k=1 (t)
  }
  const float2* c2 = (const float2*)(cw + (size_t)o*H_*2);
  bf16_t* dc = Wct + (size_t)op*(2*H_);
  for (int i = threadIdx.x; i < H_; i += 256){
    float2 v = c2[i];
    dc[i]      = __float2bfloat16(v.x);
    dc[H_ + i] = __float2bfloat16(v.y);
  }
  if (threadIdx.x == 0) bias4[j*4 + gate] = ib[o] + cb[o];
}

// ---- X (B,512,1024) f32 -> Xt (B,1025,512) bf16, Xt[b][t+1][i] = X[b][i][t] ----
__global__ void transpose_x(const float* __restrict__ X, bf16_t* __restrict__ Xt){
  __shared__ float tile[64][65];
  int b = blockIdx.z;
  int t0 = blockIdx.x*64, i0 = blockIdx.y*64;
  int c = threadIdx.x & 63;
  for (int r = threadIdx.x >> 6; r < 64; r += 4)
    tile[r][c] = X[((size_t)b*NINP_ + i0 + r)*L_ + t0 + c];
  __syncthreads();
  for (int r = threadIdx.x >> 6; r < 64; r += 4)
    Xt[((size_t)b*LP1 + t0 + r + 1)*NINP_ + i0 + c] = __float2bfloat16(tile[c][r]);
}

// ---- fused GEMM: 128x128 tile, BK=32, 4 waves (2x2), XCD-swizzled ----
// MODE 0: us4 = f16x4 gather of A*Bt + bias   (A=Xt, K=1024)
// MODE 1: gates(A*Bt + us4) -> Hnew/Cnew      (A=Hprev, K=1536)
template<int KTOT, int AROW, int MODE>
__launch_bounds__(256, 3)
__global__ void gemm_fused(const bf16_t* __restrict__ A, const bf16_t* __restrict__ Bt,
                           const float* __restrict__ bias4, f16x4* __restrict__ us4,
                           const _Float16* __restrict__ Cprev, _Float16* __restrict__ Cnew,
                           bf16_t* __restrict__ Hnew, int bn_base){
  __shared__ bf16_t As[128*32];
  __shared__ bf16_t Bs[128*32];
  const int tid = threadIdx.x;
  const int l = tid & 63;
  const int w = tid >> 6;
  const int wm = w >> 1, wn = w & 1;

  // XCD-aware bijective swizzle (nwg % 8 == 0 for all grids used)
  const int nwg = gridDim.x * gridDim.y;
  int flat = blockIdx.y * gridDim.x + blockIdx.x;
  flat = (flat & 7) * (nwg >> 3) + (flat >> 3);
  const int bm0 = (flat & 31) * 128;           // gridDim.x == 32 always
  const int bn0 = bn_base + (flat >> 5) * 128;

  f32x4 acc[4][4];
#pragma unroll
  for (int i = 0; i < 4; ++i)
#pragma unroll
    for (int jj = 0; jj < 4; ++jj)
      acc[i][jj] = (f32x4){0.f,0.f,0.f,0.f};

  // staging: each wave issues 2 A-chunks + 2 B-chunks of 1KB (16 rows x 64B)
  const int sr = l >> 2;
  const int sb = (l & 3) << 4;
  const char* ag[2]; const char* bg[2];
  char* al[2]; char* bl[2];
#pragma unroll
  for (int n = 0; n < 2; ++n){
    const int r = w*16 + n*64 + sr;
    const int m = bm0 + r;
    const int b = m >> 10, t = m & 1023;
    ag[n] = (const char*)A + ((size_t)(b*LP1 + t)*AROW)*2 + sb;
    bg[n] = (const char*)Bt + ((size_t)(bn0 + r)*KTOT)*2 + sb;
    al[n] = (char*)As + (w + n*4)*1024;
    bl[n] = (char*)Bs + (w + n*4)*1024;
  }

  const int kg = (l >> 4) << 4;   // byte offset of k-group in 64B row
  const int lr = l & 15;

  for (int kt = 0; kt < KTOT/32; ++kt){
    const int ko = kt << 6;
    gl_lds16(ag[0] + ko, al[0]);
    gl_lds16(ag[1] + ko, al[1]);
    gl_lds16(bg[0] + ko, bl[0]);
    gl_lds16(bg[1] + ko, bl[1]);
    __syncthreads();
    bf16x8 af[4], bfv[4];
#pragma unroll
    for (int f = 0; f < 4; ++f){
      af[f]  = *reinterpret_cast<const bf16x8*>((const char*)As + (wm*64 + f*16 + lr)*64 + kg);
      bfv[f] = *reinterpret_cast<const bf16x8*>((const char*)Bs + (wn*64 + f*16 + lr)*64 + kg);
    }
#pragma unroll
    for (int fm = 0; fm < 4; ++fm)
#pragma unroll
      for (int fn = 0; fn < 4; ++fn)
        acc[fm][fn] = __builtin_amdgcn_mfma_f32_16x16x32_bf16(af[fm], bfv[fn], acc[fm][fn], 0, 0, 0);
    __syncthreads();
  }

  const int jblk = (bn0 + wn*64) >> 6;
  const int j = jblk*16 + lr;
  const int rq = (l >> 4) << 2;

  if (MODE == 0){
    const float4 bz = ((const float4*)bias4)[j];
#pragma unroll
    for (int fm = 0; fm < 4; ++fm){
      const int mbase = bm0 + wm*64 + fm*16 + rq;
#pragma unroll
      for (int r = 0; r < 4; ++r){
        const int m = mbase + r;
        f16x4 v = { (_Float16)(acc[fm][0][r] + bz.x), (_Float16)(acc[fm][1][r] + bz.y),
                    (_Float16)(acc[fm][2][r] + bz.z), (_Float16)(acc[fm][3][r] + bz.w) };
        us4[(size_t)m*H_ + j] = v;
      }
    }
  } else {
#pragma unroll
    for (int fm = 0; fm < 4; ++fm){
      const int mbase = bm0 + wm*64 + fm*16 + rq;
      f16x4 uv[4]; _Float16 cp16[4]; size_t hcb[4];
#pragma unroll
      for (int r = 0; r < 4; ++r){
        const int m = mbase + r;
        const int b = m >> 10, t = m & 1023;
        uv[r] = us4[(size_t)m*H_ + j];
        hcb[r] = (size_t)(b*LP1 + t)*H_ + j;
        cp16[r] = Cprev[hcb[r]];
      }
#pragma unroll
      for (int r = 0; r < 4; ++r){
        const float ig = acc[fm][0][r] + (float)uv[r][0];
        const float og = acc[fm][1][r] + (float)uv[r][1];
        const float gg = acc[fm][2][r] + (float)uv[r][2];
        const float fg = acc[fm][3][r] + (float)uv[r][3];
        const float c  = sigf(fg)*(float)cp16[r] + sigf(ig)*tanhf_(gg);
        const float h  = sigf(og)*tanhf_(c);
        Cnew[hcb[r] + H_] = (_Float16)c;          // row t+1
        Hnew[hcb[r] + H_] = __float2bfloat16(h);
      }
    }
  }
}

// ---- iteration 0: h=c=0 (c_prev=z0c at t=0) -> elementwise gates on us4 ----
__global__ void iter0_k(const f16x4* __restrict__ us4, bf16_t* __restrict__ Hn,
                        _Float16* __restrict__ Cn){
  const int m = blockIdx.y;
  const int j = blockIdx.x*256 + threadIdx.x;
  const int b = m >> 10, t = m & 1023;
  f16x4 u = us4[(size_t)m*H_ + j];
  const float ig = (float)u[0], og = (float)u[1], gg = (float)u[2], fg = (float)u[3];
  float cp = (t == 0) ? (float)Cn[(size_t)b*LP1*H_ + j] : 0.f;
  const float c = sigf(fg)*cp + sigf(ig)*tanhf_(gg);
  const float h = sigf(og)*tanhf_(c);
  const size_t idx = (size_t)(b*LP1 + t + 1)*H_ + j;
  Cn[idx] = (_Float16)c;
  Hn[idx] = __float2bfloat16(h);
}

// ---- tail: full-channel state at t=L for z0_out (reads it8 state) ----
__global__ void tail_k(const bf16_t* __restrict__ H8, const _Float16* __restrict__ C8,
                       const f16x4* __restrict__ us4, const bf16_t* __restrict__ Wct,
                       float* __restrict__ out){
  const int b = blockIdx.y;
  const int op = blockIdx.x*256 + threadIdx.x;
  const int gate = (op >> 4) & 3, lr = op & 15;
  const int j = ((op >> 6) << 4) | lr;
  const bf16_t* a  = H8 + (size_t)(b*LP1 + 1023)*H_;   // rows 1023,1024 = h8[1022],h8[1023]
  const bf16_t* wr = Wct + (size_t)op*1536;
  float s = 0.f;
#pragma unroll 4
  for (int k2 = 0; k2 < 1536; k2 += 8){
    bf16x8 av = *reinterpret_cast<const bf16x8*>(a + k2);
    bf16x8 wv = *reinterpret_cast<const bf16x8*>(wr + k2);
#pragma unroll
    for (int u = 0; u < 8; ++u) s += (float)av[u]*(float)wv[u];
  }
  s += (float)us4[(size_t)(b*1024 + 1023)*H_ + j][gate];
  const float si = __shfl(s, lr);
  const float so = __shfl(s, lr + 16);
  const float sg = __shfl(s, lr + 32);
  const float sf = __shfl(s, lr + 48);
  if (gate == 0){
    const float cp = (float)C8[(size_t)(b*LP1 + 1023)*H_ + j];  // c8 at time 1022
    const float c = sigf(sf)*cp + sigf(si)*tanhf_(sg);
    const float h = sigf(so)*tanhf_(c);
    out[B_*L_*NOUT_ + b*2*H_ + j]      = h;
    out[B_*L_*NOUT_ + b*2*H_ + H_ + j] = c;
  }
}

// ---- finalize: out (B,L,NOUT) from it9 h ----
__global__ void finalize_k(const bf16_t* __restrict__ Hf, float* __restrict__ out){
  const int tid = blockIdx.x*256 + threadIdx.x;
  const int n = tid & 255, t = (tid >> 8) & 1023, b = tid >> 18;
  out[tid] = __bfloat162float(Hf[((size_t)b*LP1 + t + 1)*H_ + (H_ - NOUT_) + n]);
}

extern "C" void kernel_launch(void* const* d_in, const int* in_sizes, int n_in,
                              void* d_out, int out_size, void* d_ws, size_t ws_size,
                              hipStream_t stream){
  const float* X   = (const float*)d_in[0];
  const float* z0  = (const float*)d_in[1];
  const float* iw  = (const float*)d_in[2];
  const float* ib  = (const float*)d_in[3];
  const float* cw  = (const float*)d_in[4];
  const float* cbv = (const float*)d_in[5];
  float* out = (float*)d_out;

  char* ws = (char*)d_ws;
  f16x4*    us4  = (f16x4*)   (ws + 0);           // 4096*768*8  = 25165824
  bf16_t*   Xt   = (bf16_t*)  (ws + 25165824);    // 4*1025*512*2 = 4198400
  bf16_t*   Wit  = (bf16_t*)  (ws + 29364224);    // 3072*1024*2 = 6291456
  bf16_t*   Wct  = (bf16_t*)  (ws + 35655680);    // 3072*1536*2 = 9437184
  float*    bias4= (float*)   (ws + 45092864);    // 768*4*4 = 12288
  bf16_t*   Hb0  = (bf16_t*)  (ws + 45105152);    // 4*1025*768*2 = 6297600
  bf16_t*   Hb1  = (bf16_t*)  (ws + 51402752);
  _Float16* Cb0  = (_Float16*)(ws + 57700352);    // 4*1025*768*2 = 6297600
  _Float16* Cb1  = (_Float16*)(ws + 63997952);    // end = 70295552 (~67MB)

  init_k<<<12, 256, 0, stream>>>(z0, Xt, Hb0, Hb1, Cb0, Cb1);
  prep_w<<<NG_, 256, 0, stream>>>(iw, ib, cw, cbv, Wit, Wct, bias4);
  transpose_x<<<dim3(L_/64, NINP_/64, B_), 256, 0, stream>>>(X, Xt);

  // inject conv as GEMM: M=4096, N=3072, K=1024 -> us4 (fp16, gate-gathered)
  gemm_fused<1024, NINP_, 0><<<dim3(32, 24), 256, 0, stream>>>(
      Xt, Wit, bias4, us4, nullptr, nullptr, nullptr, 0);

  // iteration 0 (h=0): elementwise on us4
  iter0_k<<<dim3(3, 4096), 256, 0, stream>>>(us4, Hb0, Cb0);

  // iterations 1..8: fused GEMM (K=1536) + gates, double-buffered
  bf16_t* Hp = Hb0; _Float16* Cp = Cb0;
  bf16_t* Hn = Hb1; _Float16* Cn = Cb1;
  for (int it = 1; it <= 8; ++it){
    gemm_fused<1536, H_, 1><<<dim3(32, 24), 256, 0, stream>>>(
        Hp, Wct, nullptr, us4, Cp, Cn, Hn, 0);
    bf16_t* th = Hp; Hp = Hn; Hn = th;
    _Float16* tc = Cp; Cp = Cn; Cn = tc;
  }

  // z0_out full-channel state at t=L (from it8 state), runs before reduced it9
  tail_k<<<dim3(12, B_), 256, 0, stream>>>(Hp, Cp, us4, Wct, out);

  // iteration 9: only o'-cols [2048,3072) (j in [512,768)) are needed for out
  gemm_fused<1536, H_, 1><<<dim3(32, 8), 256, 0, stream>>>(
      Hp, Wct, nullptr, us4, Cp, Cn, Hn, 2048);

  finalize_k<<<4096, 256, 0, stream>>>(Hn, out);
}